// Round 13
// baseline (355.714 us; speedup 1.0000x reference)
//
#include <hip/hip_runtime.h>
#include <cstdint>

#define GRAPHS 512
#define HEADS 4
#define CPH 12
#define HID 48
#define NPAIR 24
#define RECW 32      // node record width in uints: [als f32x4 | xh bf16x48 | ald f32x4]
#define OUTC 10
#define WPB 4        // waves per block in agg (each wave = 2 nodes)
#define MAXBUCK 1024 // supports n <= 262144 (bucket = 256 nodes)
#define BCAP 8192    // per-bucket edge capacity (uniform-random dst: mean ~4400)
#define BCHUNK 8192

__device__ __forceinline__ float bflo(unsigned u){ return __uint_as_float(u<<16); }
__device__ __forceinline__ float bfhi(unsigned u){ return __uint_as_float(u&0xFFFF0000u); }
__device__ __forceinline__ unsigned pack_bf16(float a, float b){
    unsigned ua=__float_as_uint(a), ub=__float_as_uint(b);
    ua += 0x7FFFu + ((ua>>16)&1u);           // RNE
    ub += 0x7FFFu + ((ub>>16)&1u);
    return (ua>>16) | (ub & 0xFFFF0000u);
}

__device__ __forceinline__ void fma4(float4& a, const float4 h,
    const float4 w0, const float4 w1, const float4 w2, const float4 w3)
{
    a.x = fmaf(h.x, w0.x, a.x); a.x = fmaf(h.y, w1.x, a.x); a.x = fmaf(h.z, w2.x, a.x); a.x = fmaf(h.w, w3.x, a.x);
    a.y = fmaf(h.x, w0.y, a.y); a.y = fmaf(h.y, w1.y, a.y); a.y = fmaf(h.z, w2.y, a.y); a.y = fmaf(h.w, w3.y, a.y);
    a.z = fmaf(h.x, w0.z, a.z); a.z = fmaf(h.y, w1.z, a.z); a.z = fmaf(h.z, w2.z, a.z); a.z = fmaf(h.w, w3.z, a.z);
    a.w = fmaf(h.x, w0.w, a.w); a.w = fmaf(h.y, w1.w, a.w); a.w = fmaf(h.z, w2.w, a.w); a.w = fmaf(h.w, w3.w, a.w);
}

// ---------------- GEMM + attention-coefficient kernel (register-tiled) -------
// rec[node]: uints 0-3 = als (f32), 4-27 = xh bf16 pairs, 28-31 = ald (f32)
// 192 threads = 12 chan-slots x 16 node-slots; 6 nodes per thread (NPB=96).
template<int FIN, bool BF16IN>
__global__ __launch_bounds__(192) void gemm_al_kernel(
    const void* __restrict__ hin_, const float* __restrict__ W,
    const float* __restrict__ avs, const float* __restrict__ avd,
    unsigned* __restrict__ rec, int n)
{
    const int NPB = 96;
    const int SHW = FIN / 4 + 1;          // sH row width in float4
    __shared__ float4 sH[NPB * SHW];
    __shared__ float4 sW4[FIN * 12];
    __shared__ float sA[HID], sB[HID];
    __shared__ float sPS[NPB][13];        // per-(node,cs) attention partials, padded
    __shared__ float sPD[NPB][13];

    const int t = threadIdx.x;
    const int base = blockIdx.x * NPB;

    for (int i = t; i < FIN * 12; i += 192) sW4[i] = ((const float4*)W)[i];
    if (t < HID) { sA[t] = avs[t]; sB[t] = avd[t]; }

    if (BF16IN) {
        const unsigned* hin = (const unsigned*)hin_;
        float* sHf = (float*)sH;
        const int RW = 4 * SHW;
        for (int i = t; i < NPB * (FIN / 2); i += 192) {
            int r = i / (FIN / 2), pc = i % (FIN / 2);
            int node = base + r;
            unsigned u = (node < n) ? hin[(size_t)node * (FIN / 2) + pc] : 0u;
            sHf[r * RW + 2 * pc]     = bflo(u);
            sHf[r * RW + 2 * pc + 1] = bfhi(u);
        }
    } else {
        const float4* hin = (const float4*)hin_;
        for (int i = t; i < NPB * (FIN / 4); i += 192) {
            int r = i / (FIN / 4), q = i % (FIN / 4);
            int node = base + r;
            sH[r * SHW + q] = (node < n) ? hin[(size_t)node * (FIN / 4) + q]
                                         : float4{0.f,0.f,0.f,0.f};
        }
    }
    __syncthreads();

    const int cs = t >> 4;    // 0..11 (chans 4cs..4cs+3)
    const int ns = t & 15;    // nodes ns + 16k, k = 0..5

    float4 acc0{0.f,0.f,0.f,0.f}, acc1{0.f,0.f,0.f,0.f}, acc2{0.f,0.f,0.f,0.f};
    float4 acc3{0.f,0.f,0.f,0.f}, acc4{0.f,0.f,0.f,0.f}, acc5{0.f,0.f,0.f,0.f};

    #pragma unroll
    for (int kq = 0; kq < FIN / 4; ++kq) {
        float4 w0 = sW4[(4 * kq + 0) * 12 + cs];
        float4 w1 = sW4[(4 * kq + 1) * 12 + cs];
        float4 w2 = sW4[(4 * kq + 2) * 12 + cs];
        float4 w3 = sW4[(4 * kq + 3) * 12 + cs];
        float4 h0 = sH[(ns +  0) * SHW + kq];
        float4 h1 = sH[(ns + 16) * SHW + kq];
        float4 h2 = sH[(ns + 32) * SHW + kq];
        float4 h3 = sH[(ns + 48) * SHW + kq];
        float4 h4 = sH[(ns + 64) * SHW + kq];
        float4 h5 = sH[(ns + 80) * SHW + kq];
        fma4(acc0, h0, w0, w1, w2, w3);
        fma4(acc1, h1, w0, w1, w2, w3);
        fma4(acc2, h2, w0, w1, w2, w3);
        fma4(acc3, h3, w0, w1, w2, w3);
        fma4(acc4, h4, w0, w1, w2, w3);
        fma4(acc5, h5, w0, w1, w2, w3);
    }

    // attention partials -> unique LDS slots (no atomics)
    const float A0 = sA[4*cs], A1 = sA[4*cs+1], A2 = sA[4*cs+2], A3 = sA[4*cs+3];
    const float B0 = sB[4*cs], B1 = sB[4*cs+1], B2 = sB[4*cs+2], B3 = sB[4*cs+3];
    sPS[ns +  0][cs] = fmaf(acc0.x,A0, fmaf(acc0.y,A1, fmaf(acc0.z,A2, acc0.w*A3)));
    sPD[ns +  0][cs] = fmaf(acc0.x,B0, fmaf(acc0.y,B1, fmaf(acc0.z,B2, acc0.w*B3)));
    sPS[ns + 16][cs] = fmaf(acc1.x,A0, fmaf(acc1.y,A1, fmaf(acc1.z,A2, acc1.w*A3)));
    sPD[ns + 16][cs] = fmaf(acc1.x,B0, fmaf(acc1.y,B1, fmaf(acc1.z,B2, acc1.w*B3)));
    sPS[ns + 32][cs] = fmaf(acc2.x,A0, fmaf(acc2.y,A1, fmaf(acc2.z,A2, acc2.w*A3)));
    sPD[ns + 32][cs] = fmaf(acc2.x,B0, fmaf(acc2.y,B1, fmaf(acc2.z,B2, acc2.w*B3)));
    sPS[ns + 48][cs] = fmaf(acc3.x,A0, fmaf(acc3.y,A1, fmaf(acc3.z,A2, acc3.w*A3)));
    sPD[ns + 48][cs] = fmaf(acc3.x,B0, fmaf(acc3.y,B1, fmaf(acc3.z,B2, acc3.w*B3)));
    sPS[ns + 64][cs] = fmaf(acc4.x,A0, fmaf(acc4.y,A1, fmaf(acc4.z,A2, acc4.w*A3)));
    sPD[ns + 64][cs] = fmaf(acc4.x,B0, fmaf(acc4.y,B1, fmaf(acc4.z,B2, acc4.w*B3)));
    sPS[ns + 80][cs] = fmaf(acc5.x,A0, fmaf(acc5.y,A1, fmaf(acc5.z,A2, acc5.w*A3)));
    sPD[ns + 80][cs] = fmaf(acc5.x,B0, fmaf(acc5.y,B1, fmaf(acc5.z,B2, acc5.w*B3)));

    // xh writes (bf16 pairs 2cs, 2cs+1) as single 8B stores
    {
        int node = base + ns;
        if (node < n) {
            uint2* rp = (uint2*)(rec + (size_t)node * RECW + 4 + 2 * cs);
            *rp = uint2{pack_bf16(acc0.x, acc0.y), pack_bf16(acc0.z, acc0.w)};
        }
        node = base + ns + 16;
        if (node < n) {
            uint2* rp = (uint2*)(rec + (size_t)node * RECW + 4 + 2 * cs);
            *rp = uint2{pack_bf16(acc1.x, acc1.y), pack_bf16(acc1.z, acc1.w)};
        }
        node = base + ns + 32;
        if (node < n) {
            uint2* rp = (uint2*)(rec + (size_t)node * RECW + 4 + 2 * cs);
            *rp = uint2{pack_bf16(acc2.x, acc2.y), pack_bf16(acc2.z, acc2.w)};
        }
        node = base + ns + 48;
        if (node < n) {
            uint2* rp = (uint2*)(rec + (size_t)node * RECW + 4 + 2 * cs);
            *rp = uint2{pack_bf16(acc3.x, acc3.y), pack_bf16(acc3.z, acc3.w)};
        }
        node = base + ns + 64;
        if (node < n) {
            uint2* rp = (uint2*)(rec + (size_t)node * RECW + 4 + 2 * cs);
            *rp = uint2{pack_bf16(acc4.x, acc4.y), pack_bf16(acc4.z, acc4.w)};
        }
        node = base + ns + 80;
        if (node < n) {
            uint2* rp = (uint2*)(rec + (size_t)node * RECW + 4 + 2 * cs);
            *rp = uint2{pack_bf16(acc5.x, acc5.y), pack_bf16(acc5.z, acc5.w)};
        }
    }

    __syncthreads();
    if (t < NPB) {
        int node = base + t;
        if (node < n) {
            float4 als4, ald4;
            als4.x = sPS[t][0] + sPS[t][1]  + sPS[t][2];
            als4.y = sPS[t][3] + sPS[t][4]  + sPS[t][5];
            als4.z = sPS[t][6] + sPS[t][7]  + sPS[t][8];
            als4.w = sPS[t][9] + sPS[t][10] + sPS[t][11];
            ald4.x = sPD[t][0] + sPD[t][1]  + sPD[t][2];
            ald4.y = sPD[t][3] + sPD[t][4]  + sPD[t][5];
            ald4.z = sPD[t][6] + sPD[t][7]  + sPD[t][8];
            ald4.w = sPD[t][9] + sPD[t][10] + sPD[t][11];
            float* recf = (float*)(rec + (size_t)node * RECW);
            *(float4*)recf        = als4;   // als
            *(float4*)(recf + 28) = ald4;   // ald
        }
    }
}

// ---------------- CSR build (LDS-staged single global read of edst) ----------
__global__ __launch_bounds__(256) void passAB_kernel(
    const int* __restrict__ esrc, const int* __restrict__ edst, int E,
    int* __restrict__ gcur, unsigned* __restrict__ ebuf, int nbuck)
{
    __shared__ int lcnt[MAXBUCK];
    __shared__ int lbase[MAXBUCK];
    __shared__ int sD[BCHUNK];       // staged dst values (32 KB)
    for (int i = threadIdx.x; i < nbuck; i += 256) lcnt[i] = 0;
    __syncthreads();
    int e0 = blockIdx.x * BCHUNK, e1 = min(E, e0 + BCHUNK);
    for (int e = e0 + threadIdx.x; e < e1; e += 256) {
        int d = edst[e];
        sD[e - e0] = d;
        atomicAdd(&lcnt[d >> 8], 1);
    }
    __syncthreads();
    for (int i = threadIdx.x; i < nbuck; i += 256) {
        int c = lcnt[i];
        lbase[i] = c ? (i * BCAP + atomicAdd(&gcur[i], c)) : 0;
        lcnt[i] = 0;
    }
    __syncthreads();
    for (int e = e0 + threadIdx.x; e < e1; e += 256) {
        int d = sD[e - e0], s = esrc[e];
        int b = d >> 8;
        int rk = atomicAdd(&lcnt[b], 1);
        ebuf[lbase[b] + rk] = ((unsigned)(d & 255) << 24) | (unsigned)s;
    }
}

__global__ __launch_bounds__(1024) void bscan_kernel(
    const int* __restrict__ bcnt, int* __restrict__ boff, int nbuck, int etot)
{
    __shared__ int s[1024];
    int t = threadIdx.x;
    int v = (t < nbuck) ? bcnt[t] : 0;
    s[t] = v; __syncthreads();
    for (int off = 1; off < 1024; off <<= 1) {
        int a = (t >= off) ? s[t - off] : 0;
        __syncthreads();
        s[t] += a;
        __syncthreads();
    }
    if (t < nbuck) boff[t] = s[t] - v;
    if (t == 0) boff[nbuck] = etot;
}

__global__ __launch_bounds__(256) void passC_kernel(
    const unsigned* __restrict__ ebuf, const int* __restrict__ boff,
    const int* __restrict__ bcnt,
    int* __restrict__ rowptr, int* __restrict__ colidx, int n, int E)
{
    __shared__ int lcnt[256];
    __shared__ int sc[256];
    __shared__ int lcur[256];
    int b = blockIdx.x, t = threadIdx.x;
    int nbase = b << 8;
    lcnt[t] = 0;
    __syncthreads();
    int s0 = b * BCAP;
    int s1 = s0 + bcnt[b];
    for (int i = s0 + t; i < s1; i += 256)
        atomicAdd(&lcnt[ebuf[i] >> 24], 1);
    __syncthreads();
    sc[t] = lcnt[t]; __syncthreads();
    for (int off = 1; off < 256; off <<= 1) {
        int v = (t >= off) ? sc[t - off] : 0;
        __syncthreads();
        sc[t] += v;
        __syncthreads();
    }
    int rp = boff[b] + sc[t] - lcnt[t];
    if (nbase + t < n) rowptr[nbase + t] = rp;
    if (b == (int)gridDim.x - 1 && t == 0) rowptr[n] = E;
    lcur[t] = rp;
    __syncthreads();
    for (int i = s0 + t; i < s1; i += 256) {
        unsigned u = ebuf[i];
        int pos = atomicAdd(&lcur[u >> 24], 1);
        colidx[pos] = (int)(u & 0xFFFFFFu);
    }
}

// ---------------- aggregation: TWO nodes per wave, software-pipelined --------
// FMA phase 8-deep unrolled (8 xh gathers in flight).
__global__ __launch_bounds__(256) void agg_kernel(
    const int* __restrict__ rowptr, const int* __restrict__ colidx,
    const unsigned* __restrict__ rec,
    unsigned* __restrict__ hb, int n)
{
    __shared__ float tb[WPB][2][32][5];
    __shared__ int   sb[WPB][2][32];
    const int w = threadIdx.x >> 6, lane = threadIdx.x & 63;
    const int half = lane >> 5, l32 = lane & 31;
    const int node = (blockIdx.x * WPB + w) * 2 + half;
    const bool act = node < n;

    int start = 0, end = 0;
    if (act) { start = rowptr[node]; end = rowptr[node + 1]; }

    const unsigned* nrec = rec + (size_t)node * RECW;
    float4 asn  = act ? *(const float4*)(nrec)      : float4{0.f,0.f,0.f,0.f};
    float4 aldn = act ? *(const float4*)(nrec + 28) : float4{0.f,0.f,0.f,0.f};

    const bool fmaL = l32 < NPAIR;
    const int p  = fmaL ? l32 : 0;
    const int hh = p / 6;

    float tself;
    {
        float as_h = hh < 2 ? (hh == 0 ? asn.x : asn.y) : (hh == 2 ? asn.z : asn.w);
        float ad_h = hh < 2 ? (hh == 0 ? aldn.x : aldn.y) : (hh == 2 ? aldn.z : aldn.w);
        float ls = as_h + ad_h; ls = ls > 0.f ? ls : 0.2f * ls;
        tself = __expf(ls);
    }

    float a0 = 0.f, a1 = 0.f, a2 = 0.f, a3 = 0.f;
    float den = tself;
    if (act && fmaL) {
        unsigned u = nrec[4 + p];
        a0 = tself * bflo(u);
        a1 = tself * bfhi(u);
    }

    const char* recb = (const char*)rec;
    const int poff = 16 + 4 * p;     // byte offset of pair p within a record

    if (start < end) {
        // prologue: load chunk 0's colidx + als into registers
        int idx = start + l32; if (idx >= end) idx = end - 1;
        int s_nx = colidx[idx];
        float4 al_nx = *(const float4*)(recb + ((size_t)(unsigned)s_nx << 7));

        for (int cb = start; cb < end; cb += 32) {
            const int m = min(32, end - cb);
            // stage current chunk from registers
            {
                sb[w][half][l32] = s_nx << 7;
                float l0 = al_nx.x + aldn.x; l0 = l0 > 0.f ? l0 : 0.2f * l0;
                float l1 = al_nx.y + aldn.y; l1 = l1 > 0.f ? l1 : 0.2f * l1;
                float l2 = al_nx.z + aldn.z; l2 = l2 > 0.f ? l2 : 0.2f * l2;
                float l3 = al_nx.w + aldn.w; l3 = l3 > 0.f ? l3 : 0.2f * l3;
                tb[w][half][l32][0] = __expf(l0);
                tb[w][half][l32][1] = __expf(l1);
                tb[w][half][l32][2] = __expf(l2);
                tb[w][half][l32][3] = __expf(l3);
            }
            // issue next chunk's gathers (hide latency under FMA phase)
            const int cb2 = cb + 32;
            if (cb2 < end) {
                int idx2 = cb2 + l32; if (idx2 >= end) idx2 = end - 1;
                s_nx = colidx[idx2];
                al_nx = *(const float4*)(recb + ((size_t)(unsigned)s_nx << 7));
            }
            __builtin_amdgcn_sched_barrier(0);
            if (fmaL) {
                int j = 0;
                for (; j + 8 <= m; j += 8) {
                    int o0 = sb[w][half][j+0], o1 = sb[w][half][j+1];
                    int o2 = sb[w][half][j+2], o3 = sb[w][half][j+3];
                    int o4 = sb[w][half][j+4], o5 = sb[w][half][j+5];
                    int o6 = sb[w][half][j+6], o7 = sb[w][half][j+7];
                    float t0 = tb[w][half][j+0][hh], t1 = tb[w][half][j+1][hh];
                    float t2 = tb[w][half][j+2][hh], t3 = tb[w][half][j+3][hh];
                    float t4 = tb[w][half][j+4][hh], t5 = tb[w][half][j+5][hh];
                    float t6 = tb[w][half][j+6][hh], t7 = tb[w][half][j+7][hh];
                    unsigned u0 = *(const unsigned*)(recb + o0 + poff);
                    unsigned u1 = *(const unsigned*)(recb + o1 + poff);
                    unsigned u2 = *(const unsigned*)(recb + o2 + poff);
                    unsigned u3 = *(const unsigned*)(recb + o3 + poff);
                    unsigned u4 = *(const unsigned*)(recb + o4 + poff);
                    unsigned u5 = *(const unsigned*)(recb + o5 + poff);
                    unsigned u6 = *(const unsigned*)(recb + o6 + poff);
                    unsigned u7 = *(const unsigned*)(recb + o7 + poff);
                    den += ((t0 + t1) + (t2 + t3)) + ((t4 + t5) + (t6 + t7));
                    a0 = fmaf(t0, bflo(u0), a0); a1 = fmaf(t0, bfhi(u0), a1);
                    a2 = fmaf(t1, bflo(u1), a2); a3 = fmaf(t1, bfhi(u1), a3);
                    a0 = fmaf(t2, bflo(u2), a0); a1 = fmaf(t2, bfhi(u2), a1);
                    a2 = fmaf(t3, bflo(u3), a2); a3 = fmaf(t3, bfhi(u3), a3);
                    a0 = fmaf(t4, bflo(u4), a0); a1 = fmaf(t4, bfhi(u4), a1);
                    a2 = fmaf(t5, bflo(u5), a2); a3 = fmaf(t5, bfhi(u5), a3);
                    a0 = fmaf(t6, bflo(u6), a0); a1 = fmaf(t6, bfhi(u6), a1);
                    a2 = fmaf(t7, bflo(u7), a2); a3 = fmaf(t7, bfhi(u7), a3);
                }
                for (; j + 4 <= m; j += 4) {
                    int o0 = sb[w][half][j+0], o1 = sb[w][half][j+1];
                    int o2 = sb[w][half][j+2], o3 = sb[w][half][j+3];
                    float t0 = tb[w][half][j+0][hh], t1 = tb[w][half][j+1][hh];
                    float t2 = tb[w][half][j+2][hh], t3 = tb[w][half][j+3][hh];
                    unsigned u0 = *(const unsigned*)(recb + o0 + poff);
                    unsigned u1 = *(const unsigned*)(recb + o1 + poff);
                    unsigned u2 = *(const unsigned*)(recb + o2 + poff);
                    unsigned u3 = *(const unsigned*)(recb + o3 + poff);
                    den += (t0 + t1) + (t2 + t3);
                    a0 = fmaf(t0, bflo(u0), a0); a1 = fmaf(t0, bfhi(u0), a1);
                    a2 = fmaf(t1, bflo(u1), a2); a3 = fmaf(t1, bfhi(u1), a3);
                    a0 = fmaf(t2, bflo(u2), a0); a1 = fmaf(t2, bfhi(u2), a1);
                    a2 = fmaf(t3, bflo(u3), a2); a3 = fmaf(t3, bfhi(u3), a3);
                }
                for (; j < m; ++j) {
                    int o0 = sb[w][half][j];
                    float t0 = tb[w][half][j][hh];
                    unsigned u0 = *(const unsigned*)(recb + o0 + poff);
                    den += t0;
                    a0 = fmaf(t0, bflo(u0), a0); a1 = fmaf(t0, bfhi(u0), a1);
                }
            }
            __builtin_amdgcn_sched_barrier(0);
        }
    }

    if (act && fmaL) {
        float inv = 1.f / (den + 1e-16f);
        float vLo = (a0 + a2) * inv; vLo = vLo > 0.f ? vLo : 0.f;
        float vHi = (a1 + a3) * inv; vHi = vHi > 0.f ? vHi : 0.f;
        hb[(size_t)node * NPAIR + p] = pack_bf16(vLo, vHi);
    }
}

// ---------------- global mean pool + MLP layer 1 (fused) ---------------------
__global__ __launch_bounds__(256) void pool_mlp1_kernel(
    const unsigned* __restrict__ hb, const int* __restrict__ batch,
    const float* __restrict__ W1, const float* __restrict__ b1,
    float* __restrict__ z, int n)
{
    __shared__ float sLo[8][NPAIR];
    __shared__ float sHi[8][NPAIR];
    __shared__ float sg[HID];
    int g = blockIdx.x;
    int lo = 0, hi = n;
    while (lo < hi) { int mid = (lo + hi) >> 1; if (batch[mid] < g) lo = mid + 1; else hi = mid; }
    int start = lo;
    lo = start; hi = n;
    while (lo < hi) { int mid = (lo + hi) >> 1; if (batch[mid] < g + 1) lo = mid + 1; else hi = mid; }
    int end = lo;

    int r = threadIdx.x >> 5;        // 0..7
    int p = threadIdx.x & 31;        // active < 24
    if (p < NPAIR) {
        float aLo = 0.f, aHi = 0.f;
        for (int i = start + r; i < end; i += 8) {
            unsigned u = hb[(size_t)i * NPAIR + p];
            aLo += bflo(u); aHi += bfhi(u);
        }
        sLo[r][p] = aLo; sHi[r][p] = aHi;
    }
    __syncthreads();
    if (threadIdx.x < NPAIR) {
        float l = 0.f, h2 = 0.f;
        #pragma unroll
        for (int rr = 0; rr < 8; ++rr) { l += sLo[rr][threadIdx.x]; h2 += sHi[rr][threadIdx.x]; }
        float cnt = (float)(end > start ? end - start : 1);
        sg[2 * threadIdx.x]     = l / cnt;
        sg[2 * threadIdx.x + 1] = h2 / cnt;
    }
    __syncthreads();
    int c = threadIdx.x;
    if (c < HID) {
        float acc = b1[c];
        #pragma unroll
        for (int k = 0; k < HID; ++k) acc = fmaf(sg[k], W1[k * HID + c], acc);
        z[g * HID + c] = acc;
    }
}

// ---------------- BatchNorm stats over 512 rows ----------------
__global__ __launch_bounds__(256) void bn_stats_kernel(
    const float* __restrict__ z, float* __restrict__ mu, float* __restrict__ rsig)
{
    int j = blockIdx.x;
    int t = threadIdx.x;
    float s = 0.f, s2 = 0.f;
    for (int i = t; i < GRAPHS; i += 256) {
        float v = z[i * HID + j];
        s += v; s2 += v * v;
    }
    __shared__ float rs[256], rs2[256];
    rs[t] = s; rs2[t] = s2; __syncthreads();
    for (int off = 128; off > 0; off >>= 1) {
        if (t < off) { rs[t] += rs[t + off]; rs2[t] += rs2[t + off]; }
        __syncthreads();
    }
    if (t == 0) {
        float m = rs[0] / GRAPHS;
        float var = rs2[0] / GRAPHS - m * m;
        mu[j] = m;
        rsig[j] = rsqrtf(var + 1e-5f);
    }
}

// ---------------- BN + ReLU + Linear2 + softmax heads ----------------
__global__ __launch_bounds__(64) void head_kernel(
    const float* __restrict__ z, const float* __restrict__ mu, const float* __restrict__ rsig,
    const float* __restrict__ gamma, const float* __restrict__ beta,
    const float* __restrict__ W2, const float* __restrict__ b2,
    float* __restrict__ out)
{
    __shared__ float zn[HID];
    __shared__ float lastv[OUTC];
    __shared__ float red[2];
    int g = blockIdx.x;
    int t = threadIdx.x;
    if (t < HID) {
        float v = (z[g * HID + t] - mu[t]) * rsig[t] * gamma[t] + beta[t];
        zn[t] = v > 0.f ? v : 0.f;
    }
    __syncthreads();
    if (t < OUTC) {
        float acc = b2[t];
        #pragma unroll
        for (int k = 0; k < HID; ++k) acc = fmaf(zn[k], W2[k * OUTC + t], acc);
        lastv[t] = acc;
    }
    __syncthreads();
    if (t == 0) {
        float m = lastv[0];
        for (int o = 1; o < OUTC; ++o) m = fmaxf(m, lastv[o]);
        float se = 0.f;
        for (int o = 0; o < OUTC; ++o) se += expf(lastv[o] - m);
        red[0] = m; red[1] = logf(se);
    }
    __syncthreads();
    if (t < OUTC) {
        float l = lastv[t];
        float lp = l - red[0] - red[1];
        out[g * OUTC + t] = lp;
        out[GRAPHS * OUTC + g * OUTC + t] = expf(lp);
        out[2 * GRAPHS * OUTC + g * OUTC + t] = l;
    }
}

extern "C" void kernel_launch(void* const* d_in, const int* in_sizes, int n_in,
                              void* d_out, int out_size, void* d_ws, size_t ws_size,
                              hipStream_t stream)
{
    const float* x     = (const float*)d_in[0];
    const int*   ei    = (const int*)  d_in[1];
    const int*   batch = (const int*)  d_in[3];
    const float* Wg0 = (const float*)d_in[4];
    const float* as0 = (const float*)d_in[5];
    const float* ad0 = (const float*)d_in[6];
    const float* Wg1 = (const float*)d_in[7];
    const float* as1 = (const float*)d_in[8];
    const float* ad1 = (const float*)d_in[9];
    const float* Wg2 = (const float*)d_in[10];
    const float* as2 = (const float*)d_in[11];
    const float* ad2 = (const float*)d_in[12];
    const float* mW1 = (const float*)d_in[13];
    const float* mb1 = (const float*)d_in[14];
    const float* gamma = (const float*)d_in[15];
    const float* beta  = (const float*)d_in[16];
    const float* mW2 = (const float*)d_in[17];
    const float* mb2 = (const float*)d_in[18];

    const int n  = in_sizes[3];
    const int E  = in_sizes[1] / 2;
    const int FIN0 = in_sizes[0] / n;
    const int nbuck = (n + 255) >> 8;

    // workspace layout (d_ws assumed >= 256B aligned)
    unsigned* rec = (unsigned*)d_ws;                 // [n][32] node records, 128B each
    unsigned* hb  = rec + (size_t)n * RECW;          // [n][24] bf16 pairs
    float* zbuf  = (float*)(hb + (size_t)n * NPAIR); // [512][48]
    float* mu    = zbuf + GRAPHS * HID;              // [48]
    float* rsig  = mu + HID;                         // [48]
    int* rowptr  = (int*)(rsig + HID);               // [n+1]
    int* boff    = rowptr + (n + 1);                 // [MAXBUCK+1]
    int* gcur    = boff + (MAXBUCK + 1);             // [MAXBUCK] zeroed
    unsigned* ebuf = (unsigned*)(gcur + MAXBUCK);    // [nbuck*BCAP]
    int* colidx  = (int*)(ebuf + (size_t)nbuck * BCAP); // [E]

    const int* esrc = ei;
    const int* edst = ei + E;

    // ---- CSR build (2 edge passes) ----
    hipMemsetAsync(gcur, 0, MAXBUCK * sizeof(int), stream);
    passAB_kernel<<<(E + BCHUNK - 1) / BCHUNK, 256, 0, stream>>>(esrc, edst, E, gcur, ebuf, nbuck);
    bscan_kernel<<<1, 1024, 0, stream>>>(gcur, boff, nbuck, E);
    passC_kernel<<<nbuck, 256, 0, stream>>>(ebuf, boff, gcur, rowptr, colidx, n, E);

    const int gemm_blocks = (n + 95) / 96;
    const int agg_blocks  = (n + 2 * WPB - 1) / (2 * WPB);

    // layer 0 (f32 input)
    if (FIN0 == 64)
        gemm_al_kernel<64, false><<<gemm_blocks, 192, 0, stream>>>(x, Wg0, as0, ad0, rec, n);
    else
        gemm_al_kernel<48, false><<<gemm_blocks, 192, 0, stream>>>(x, Wg0, as0, ad0, rec, n);
    agg_kernel<<<agg_blocks, 256, 0, stream>>>(rowptr, colidx, rec, hb, n);
    // layers 1, 2 (bf16 input)
    gemm_al_kernel<48, true><<<gemm_blocks, 192, 0, stream>>>(hb, Wg1, as1, ad1, rec, n);
    agg_kernel<<<agg_blocks, 256, 0, stream>>>(rowptr, colidx, rec, hb, n);
    gemm_al_kernel<48, true><<<gemm_blocks, 192, 0, stream>>>(hb, Wg2, as2, ad2, rec, n);
    agg_kernel<<<agg_blocks, 256, 0, stream>>>(rowptr, colidx, rec, hb, n);

    pool_mlp1_kernel<<<GRAPHS, 256, 0, stream>>>(hb, batch, mW1, mb1, zbuf, n);
    bn_stats_kernel<<<HID, 256, 0, stream>>>(zbuf, mu, rsig);
    head_kernel<<<GRAPHS, 64, 0, stream>>>(zbuf, mu, rsig, gamma, beta, mW2, mb2, (float*)d_out);
}